// Round 10
// baseline (887.782 us; speedup 1.0000x reference)
//
#include <hip/hip_runtime.h>
#include <hip/hip_bf16.h>
#include <cstdint>
#include <cstddef>

typedef short bf16x8 __attribute__((ext_vector_type(8)));
typedef float f32x4 __attribute__((ext_vector_type(4)));

static __device__ __forceinline__ unsigned short f2bf(float f) {
    union { float f; uint32_t u; } c; c.f = f;
    uint32_t r = c.u + 0x7FFFu + ((c.u >> 16) & 1u);
    return (unsigned short)(r >> 16);
}
static __device__ __forceinline__ float bf2f_lo(uint32_t w) {
    union { uint32_t u; float f; } c; c.u = w << 16; return c.f;
}
static __device__ __forceinline__ float bf2f_hi(uint32_t w) {
    union { uint32_t u; float f; } c; c.u = w & 0xffff0000u; return c.f;
}
static __device__ __forceinline__ float fast_tanh(float x) {
    float e = __expf(2.0f * x);
    return 1.0f - 2.0f / (e + 1.0f);
}
static __device__ __forceinline__ float softplus_f(float x) {
    return fmaxf(x, 0.0f) + log1pf(__expf(-fabsf(x)));
}

#define GLOAD_LDS16(g, l) \
    __builtin_amdgcn_global_load_lds((const __attribute__((address_space(1))) void*)(g), \
                                     (__attribute__((address_space(3))) void*)(l), 16, 0, 0)

// ---------------- f32 -> bf16 conversion, 5 segments in one launch ----------
__global__ __launch_bounds__(256) void k_convert(
    const float* __restrict__ s0, const float* __restrict__ s1,
    const float* __restrict__ s2, const float* __restrict__ s3,
    const float* __restrict__ s4,
    unsigned short* __restrict__ d0, unsigned short* __restrict__ d1,
    unsigned short* __restrict__ d2, unsigned short* __restrict__ d3,
    unsigned short* __restrict__ d4,
    int n0, int n1, int n2, int n3, int n4)
{
    int i = blockIdx.x * 256 + threadIdx.x; // float4 index
    int c0 = n0 >> 2, c1 = c0 + (n1 >> 2), c2 = c1 + (n2 >> 2),
        c3 = c2 + (n3 >> 2), c4 = c3 + (n4 >> 2);
    if (i >= c4) return;
    const float* s; unsigned short* d; int j;
    if (i < c0)      { s = s0; d = d0; j = i; }
    else if (i < c1) { s = s1; d = d1; j = i - c0; }
    else if (i < c2) { s = s2; d = d2; j = i - c1; }
    else if (i < c3) { s = s3; d = d3; j = i - c2; }
    else             { s = s4; d = d4; j = i - c3; }
    float4 v = reinterpret_cast<const float4*>(s)[j];
    ushort4 o;
    o.x = f2bf(v.x); o.y = f2bf(v.y); o.z = f2bf(v.z); o.w = f2bf(v.w);
    reinterpret_cast<ushort4*>(d)[j] = o;
}

// ---------------- projection GEMM: out[m,f] = sum_d A[m,d]*W[f,d] + bias[f] --
__global__ __launch_bounds__(256) void k_proj(
    const unsigned short* __restrict__ A,   // [M][512] bf16
    const unsigned short* __restrict__ W,   // [1024][512] bf16
    const float* __restrict__ bias,         // [1024]
    float* __restrict__ out)                // [M][1024] f32
{
    __shared__ unsigned short As[32 * 512];
    const int tid = threadIdx.x;
    const int m0 = blockIdx.x * 32;
    const int c0 = blockIdx.y * 128;
    {
        int row = tid >> 3;
        const unsigned short* src = A + (size_t)(m0 + row) * 512;
        unsigned int base = row * 1024;
        unsigned int sw = (row & 7) << 4;
        #pragma unroll
        for (int c = 0; c < 8; ++c) {
            int col = (tid & 7) * 8 + c * 64;
            bf16x8 v = *reinterpret_cast<const bf16x8*>(src + col);
            *reinterpret_cast<bf16x8*>(
                reinterpret_cast<char*>(As) + ((base + col * 2) ^ sw)) = v;
        }
    }
    __syncthreads();
    const int w = tid >> 6, l = tid & 63;
    const int lr = l & 15, lkb = (l >> 4) * 8;
    f32x4 acc[2][2] = {};
    const int colbase = c0 + w * 32;
    const unsigned short* Wb = W + (size_t)(colbase + lr) * 512 + lkb;
    const unsigned int sw = (lr & 7) << 4;
    for (int ks = 0; ks < 16; ++ks) {
        unsigned int kb = (ks * 32 + lkb) * 2;
        bf16x8 a0 = *reinterpret_cast<const bf16x8*>(
            reinterpret_cast<const char*>(As) + ((lr * 1024 + kb) ^ sw));
        bf16x8 a1 = *reinterpret_cast<const bf16x8*>(
            reinterpret_cast<const char*>(As) + (((16 + lr) * 1024 + kb) ^ sw));
        #pragma unroll
        for (int nf = 0; nf < 2; ++nf) {
            bf16x8 b = *reinterpret_cast<const bf16x8*>(Wb + nf * 16 * 512 + ks * 32);
            acc[0][nf] = __builtin_amdgcn_mfma_f32_16x16x32_bf16(a0, b, acc[0][nf], 0, 0, 0);
            acc[1][nf] = __builtin_amdgcn_mfma_f32_16x16x32_bf16(a1, b, acc[1][nf], 0, 0, 0);
        }
    }
    const int qr = (l >> 4) * 4;
    #pragma unroll
    for (int nf = 0; nf < 2; ++nf) {
        int col = colbase + nf * 16 + lr;
        float bv = bias[col];
        #pragma unroll
        for (int mf = 0; mf < 2; ++mf)
            #pragma unroll
            for (int r = 0; r < 4; ++r)
                out[(size_t)(m0 + mf * 16 + qr + r) * 1024 + col] = acc[mf][nf][r] + bv;
    }
}

// ---------------- A = tanh(enc+dec) -> bf16, interleaved into out -----------
// Row r of out (4096 B): bytes [0,2048) hold A[r][0..1023] bf16.
__global__ __launch_bounds__(256) void k_tanhA(
    const float* __restrict__ enc_f,   // [1600][1024]
    const float* __restrict__ dec_f,   // [320][1024]
    char* __restrict__ outb)
{
    const int NG = 128000 * 128;       // 16B groups
    for (int g = blockIdx.x * 256 + threadIdx.x; g < NG; g += gridDim.x * 256) {
        int row = g >> 7, c8 = g & 127;
        int bt = row / 80;
        int u = row - bt * 80;
        int b = bt / 400;
        const float* ep = enc_f + (size_t)bt * 1024 + c8 * 8;
        const float* dp = dec_f + (size_t)(b * 80 + u) * 1024 + c8 * 8;
        float4 e0 = *(const float4*)ep, e1 = *(const float4*)(ep + 4);
        float4 f0 = *(const float4*)dp, f1 = *(const float4*)(dp + 4);
        uint4 pk;
        pk.x = (uint32_t)f2bf(fast_tanh(e0.x + f0.x)) | ((uint32_t)f2bf(fast_tanh(e0.y + f0.y)) << 16);
        pk.y = (uint32_t)f2bf(fast_tanh(e0.z + f0.z)) | ((uint32_t)f2bf(fast_tanh(e0.w + f0.w)) << 16);
        pk.z = (uint32_t)f2bf(fast_tanh(e1.x + f1.x)) | ((uint32_t)f2bf(fast_tanh(e1.y + f1.y)) << 16);
        pk.w = (uint32_t)f2bf(fast_tanh(e1.z + f1.z)) | ((uint32_t)f2bf(fast_tanh(e1.w + f1.w)) << 16);
        *(uint4*)(outb + (size_t)row * 4096 + c8 * 16) = pk;
    }
}

// ---------------- main GEMM: logits = A @ Wfc^T + bias (bf16 out) -----------
// 256x256 tile, BK=64, 1024 thr = 16 waves (4x4 grid, wave tile 64x64 ->
// acc 16xf32x4 = 64 VGPR -> 4 waves/SIMD occupancy). 2x64KB LDS dbuf,
// 4 phases/tile, counted vmcnt(2) boundaries (A of t+2 stays in flight),
// B(t+1) staged phases 1-2, A(t+2) staged after phase-3 barrier.
__global__ __launch_bounds__(1024, 2) void k_gemm(
    const unsigned short* __restrict__ Wfc,   // [1024][1024] bf16
    const float* __restrict__ bfc,            // [1024]
    char* __restrict__ outb)                  // A in [0,2048), logits out [2048,4096)
{
    extern __shared__ char smem[];            // 2 x (32KB A + 32KB B)
    const int tid = threadIdx.x;
    const int w = tid >> 6, l = tid & 63;
    const int lr = l & 15, q = l >> 4;
    const int wm = w >> 2, wn = w & 3;

    // grid 2000 = 8 XCDs x 250; within XCD: np fastest (4 N-panels share A)
    const int bid = (int)blockIdx.x;
    const int g = (bid & 7) * 250 + (bid >> 3);
    const size_t R0 = (size_t)(g >> 2) * 256;
    const int n0 = (g & 3) * 256;

    // staging source (pre-swizzled): per-thread chunks i=0,1 at
    // dest d = tid*16 + i*16384 (linear); L = d ^ (((d>>7)&7)<<4);
    // row = L>>7 (0..255), kb = L&127
    const char* sA[2]; const char* sB[2];
    #pragma unroll
    for (int i = 0; i < 2; ++i) {
        unsigned d = (unsigned)tid * 16 + i * 16384;
        unsigned L = d ^ (((d >> 7) & 7u) << 4);
        unsigned row = L >> 7, kb = L & 127u;
        sA[i] = outb + (R0 + row) * 4096 + kb;
        sB[i] = (const char*)Wfc + (size_t)(n0 + row) * 2048 + kb;
    }
    char* const dbase = smem + tid * 16;

#define STG_A(buf, T) do { \
    GLOAD_LDS16(sA[0] + (T) * 128, dbase + (buf)); \
    GLOAD_LDS16(sA[1] + (T) * 128, dbase + (buf) + 16384); \
} while (0)
#define STG_B0(buf, T) do { \
    GLOAD_LDS16(sB[0] + (T) * 128, dbase + (buf) + 32768); } while (0)
#define STG_B1(buf, T) do { \
    GLOAD_LDS16(sB[1] + (T) * 128, dbase + (buf) + 49152); } while (0)

    // fragment read offsets
    const unsigned key = (unsigned)((lr & 7) << 4);
    const unsigned kx0 = (unsigned)(q * 16) ^ key;
    const unsigned kx1 = (unsigned)(q * 16 + 64) ^ key;
    const unsigned abase = (unsigned)((wm * 64 + lr) * 128);            // + mf*2048
    const unsigned bbase = (unsigned)(32768 + (wn * 64 + lr) * 128);    // + nf*2048

    f32x4 acc[4][4] = {};   // [mf][nf]
    bf16x8 af[4], bfr[2];

#define LDA(h) do { \
    const unsigned _kx = (h) ? kx1 : kx0; \
    _Pragma("unroll") \
    for (int mf = 0; mf < 4; ++mf) \
        af[mf] = *(const bf16x8*)(smem + cb + abase + mf * 2048 + _kx); \
} while (0)
#define LDB2(h, gg) do { \
    const unsigned _kx = (h) ? kx1 : kx0; \
    bfr[0] = *(const bf16x8*)(smem + cb + bbase + ((gg) * 2 + 0) * 2048 + _kx); \
    bfr[1] = *(const bf16x8*)(smem + cb + bbase + ((gg) * 2 + 1) * 2048 + _kx); \
} while (0)
#define MFQ(gg) do { \
    __builtin_amdgcn_s_setprio(1); \
    _Pragma("unroll") \
    for (int j = 0; j < 2; ++j) \
        _Pragma("unroll") \
        for (int mf = 0; mf < 4; ++mf) \
            acc[mf][(gg) * 2 + j] = __builtin_amdgcn_mfma_f32_16x16x32_bf16( \
                bfr[j], af[mf], acc[mf][(gg) * 2 + j], 0, 0, 0); \
    __builtin_amdgcn_s_setprio(0); \
} while (0)
#define BAR __builtin_amdgcn_s_barrier()

    // prologue: tile0 A+B (buf0) + tile1 A (buf1, stays in flight)
    STG_A(0u, 0);
    STG_B0(0u, 0);
    STG_B1(0u, 0);
    STG_A(65536u, 1);
    asm volatile("s_waitcnt vmcnt(2)" ::: "memory");
    BAR;
    __builtin_amdgcn_sched_barrier(0);

    #pragma unroll 2
    for (int t = 0; t < 16; ++t) {
        const unsigned cb = (unsigned)(t & 1) * 65536u;
        const unsigned nb = cb ^ 65536u;
        const bool s1 = (t + 1 < 16), s2 = (t + 2 < 16);
        // phase 0
        LDA(0); LDB2(0, 0);
        BAR;
        MFQ(0);
        // phase 1: stage B-chunk0 of t+1 into non-current buf
        LDB2(0, 1);
        if (s1) STG_B0(nb, t + 1);
        BAR;
        MFQ(1);
        // phase 2: stage B-chunk1 of t+1
        LDA(1); LDB2(1, 1);
        if (s1) STG_B1(nb, t + 1);
        BAR;
        MFQ(1);
        // phase 3: after BAR, all waves' A-reads of cb complete -> overwrite
        // cb's A region with tile t+2 (longest-latency loads, ~5-phase cover)
        LDB2(1, 0);
        BAR;
        if (s2) STG_A(cb, t + 2);
        MFQ(0);
        // boundary: counted wait -- only t+2's 2 A-loads remain in flight
        if (t < 14) {
            asm volatile("s_waitcnt vmcnt(2)" ::: "memory");
            BAR;
            __builtin_amdgcn_sched_barrier(0);
        } else if (t == 14) {
            asm volatile("s_waitcnt vmcnt(0)" ::: "memory");
            BAR;
            __builtin_amdgcn_sched_barrier(0);
        }
    }
#undef LDA
#undef LDB2
#undef MFQ
#undef BAR
#undef STG_A
#undef STG_B0
#undef STG_B1

    // epilogue: bias + pack bf16 + 8B stores (4 consecutive vocab per lane)
    #pragma unroll
    for (int nf = 0; nf < 4; ++nf) {
        const int v = n0 + wn * 64 + nf * 16 + q * 4;
        float4 bv = *(const float4*)(bfc + v);
        #pragma unroll
        for (int mf = 0; mf < 4; ++mf) {
            f32x4 a = acc[mf][nf];
            uint2 pk;
            pk.x = (uint32_t)f2bf(a[0] + bv.x) | ((uint32_t)f2bf(a[1] + bv.y) << 16);
            pk.y = (uint32_t)f2bf(a[2] + bv.z) | ((uint32_t)f2bf(a[3] + bv.w) << 16);
            size_t m = R0 + (size_t)(wm * 64 + mf * 16 + lr);
            *(uint2*)(outb + m * 4096 + 2048 + (size_t)v * 2) = pk;
        }
    }
}

// ---------------- softmax/blank epilogue pass --------------------------------
__global__ __launch_bounds__(256) void k_softmax(char* __restrict__ outb)
{
    const int row = blockIdx.x * 4 + (threadIdx.x >> 6);
    const int l = threadIdx.x & 63;
    const char* lp = outb + (size_t)row * 4096 + 2048 + l * 32;
    uint4 wa = *(const uint4*)lp;
    uint4 wb = *(const uint4*)(lp + 16);
    float v[16];
    uint32_t wd[8] = { wa.x, wa.y, wa.z, wa.w, wb.x, wb.y, wb.z, wb.w };
    #pragma unroll
    for (int i = 0; i < 8; ++i) { v[2*i] = bf2f_lo(wd[i]); v[2*i+1] = bf2f_hi(wd[i]); }

    float l0 = __shfl(v[0], 0);
    float m = (l == 0) ? -3.0e38f : v[0];
    #pragma unroll
    for (int i = 1; i < 16; ++i) m = fmaxf(m, v[i]);
    #pragma unroll
    for (int s = 1; s < 64; s <<= 1) m = fmaxf(m, __shfl_xor(m, s));
    float s = (l == 0) ? 0.0f : __expf(v[0] - m);
    #pragma unroll
    for (int i = 1; i < 16; ++i) s += __expf(v[i] - m);
    #pragma unroll
    for (int sh = 1; sh < 64; sh <<= 1) s += __shfl_xor(s, sh);

    float lse = m + __logf(s);
    float fin = -lse - softplus_f(l0);     // log_sigmoid(-l0) - lse
    float f0v = -softplus_f(-l0);          // log_sigmoid(l0)

    float* op = (float*)(outb + (size_t)row * 4096) + l * 16;
    #pragma unroll
    for (int c = 0; c < 4; ++c) {
        f32x4 o;
        o[0] = v[4*c+0] + fin; o[1] = v[4*c+1] + fin;
        o[2] = v[4*c+2] + fin; o[3] = v[4*c+3] + fin;
        if (l == 0 && c == 0) o[0] = f0v;
        __builtin_nontemporal_store(o, (f32x4*)(op + 4*c));
    }
}

extern "C" void kernel_launch(void* const* d_in, const int* in_sizes, int n_in,
                              void* d_out, int out_size, void* d_ws, size_t ws_size,
                              hipStream_t stream)
{
    const float* encoder = (const float*)d_in[0]; // [4,400,512]
    const float* decoder = (const float*)d_in[1]; // [4,80,512]
    const float* W_enc   = (const float*)d_in[2]; // [1024,512]
    const float* b_enc   = (const float*)d_in[3]; // [1024]
    const float* W_dec   = (const float*)d_in[4]; // [1024,512]
    const float* b_dec   = (const float*)d_in[5]; // [1024]
    const float* W_fc    = (const float*)d_in[6]; // [1024,1024]
    const float* b_fc    = (const float*)d_in[7]; // [1024]
    char* outb = (char*)d_out;

    char* ws = (char*)d_ws;
    float*          enc_f  = (float*)(ws);                      // 1600*1024 f32
    float*          dec_f  = (float*)(ws + 6553600);            // 320*1024 f32
    unsigned short* Wfc_h  = (unsigned short*)(ws + 7864320);   // 1024*1024 bf16
    unsigned short* Wenc_h = (unsigned short*)(ws + 9961472);   // 1024*512 bf16
    unsigned short* Wdec_h = (unsigned short*)(ws + 11010048);  // 1024*512 bf16
    unsigned short* encI_h = (unsigned short*)(ws + 12058624);  // 1600*512 bf16
    unsigned short* decI_h = (unsigned short*)(ws + 13697024);  // 320*512 bf16

    const int nEnc = 4 * 400 * 512, nDec = 4 * 80 * 512;
    const int nWe = 1024 * 512, nWd = 1024 * 512, nWf = 1024 * 1024;
    const int totalF4 = (nEnc + nDec + nWe + nWd + nWf) >> 2;
    k_convert<<<(totalF4 + 255) / 256, 256, 0, stream>>>(
        encoder, decoder, W_enc, W_dec, W_fc,
        encI_h, decI_h, Wenc_h, Wdec_h, Wfc_h,
        nEnc, nDec, nWe, nWd, nWf);

    k_proj<<<dim3(1600 / 32, 8), 256, 0, stream>>>(encI_h, Wenc_h, b_enc, enc_f);
    k_proj<<<dim3(320 / 32, 8), 256, 0, stream>>>(decI_h, Wdec_h, b_dec, dec_f);

    k_tanhA<<<4096, 256, 0, stream>>>(enc_f, dec_f, outb);

    const int GEMM_SMEM = 131072;
    hipFuncSetAttribute(reinterpret_cast<const void*>(k_gemm),
                        hipFuncAttributeMaxDynamicSharedMemorySize, GEMM_SMEM);
    k_gemm<<<2000, 1024, GEMM_SMEM, stream>>>(Wfc_h, b_fc, outb);

    k_softmax<<<32000, 256, 0, stream>>>(outb);
}

// Round 11
// 645.367 us; speedup vs baseline: 1.3756x; 1.3756x over previous
//
#include <hip/hip_runtime.h>
#include <hip/hip_bf16.h>
#include <cstdint>
#include <cstddef>

typedef short bf16x8 __attribute__((ext_vector_type(8)));
typedef float f32x4 __attribute__((ext_vector_type(4)));

static __device__ __forceinline__ unsigned short f2bf(float f) {
    union { float f; uint32_t u; } c; c.f = f;
    uint32_t r = c.u + 0x7FFFu + ((c.u >> 16) & 1u);
    return (unsigned short)(r >> 16);
}
static __device__ __forceinline__ float bf2f_lo(uint32_t w) {
    union { uint32_t u; float f; } c; c.u = w << 16; return c.f;
}
static __device__ __forceinline__ float bf2f_hi(uint32_t w) {
    union { uint32_t u; float f; } c; c.u = w & 0xffff0000u; return c.f;
}
static __device__ __forceinline__ float fast_tanh(float x) {
    float e = __expf(2.0f * x);
    return 1.0f - 2.0f / (e + 1.0f);
}
static __device__ __forceinline__ float softplus_f(float x) {
    return fmaxf(x, 0.0f) + log1pf(__expf(-fabsf(x)));
}

#define GLOAD_LDS16(g, l) \
    __builtin_amdgcn_global_load_lds((const __attribute__((address_space(1))) void*)(g), \
                                     (__attribute__((address_space(3))) void*)(l), 16, 0, 0)

// ---------------- f32 -> bf16 conversion, 5 segments in one launch ----------
__global__ __launch_bounds__(256) void k_convert(
    const float* __restrict__ s0, const float* __restrict__ s1,
    const float* __restrict__ s2, const float* __restrict__ s3,
    const float* __restrict__ s4,
    unsigned short* __restrict__ d0, unsigned short* __restrict__ d1,
    unsigned short* __restrict__ d2, unsigned short* __restrict__ d3,
    unsigned short* __restrict__ d4,
    int n0, int n1, int n2, int n3, int n4)
{
    int i = blockIdx.x * 256 + threadIdx.x; // float4 index
    int c0 = n0 >> 2, c1 = c0 + (n1 >> 2), c2 = c1 + (n2 >> 2),
        c3 = c2 + (n3 >> 2), c4 = c3 + (n4 >> 2);
    if (i >= c4) return;
    const float* s; unsigned short* d; int j;
    if (i < c0)      { s = s0; d = d0; j = i; }
    else if (i < c1) { s = s1; d = d1; j = i - c0; }
    else if (i < c2) { s = s2; d = d2; j = i - c1; }
    else if (i < c3) { s = s3; d = d3; j = i - c2; }
    else             { s = s4; d = d4; j = i - c3; }
    float4 v = reinterpret_cast<const float4*>(s)[j];
    ushort4 o;
    o.x = f2bf(v.x); o.y = f2bf(v.y); o.z = f2bf(v.z); o.w = f2bf(v.w);
    reinterpret_cast<ushort4*>(d)[j] = o;
}

// ---------------- projection GEMM: out[m,f] = sum_d A[m,d]*W[f,d] + bias[f] --
__global__ __launch_bounds__(256) void k_proj(
    const unsigned short* __restrict__ A,   // [M][512] bf16
    const unsigned short* __restrict__ W,   // [1024][512] bf16
    const float* __restrict__ bias,         // [1024]
    float* __restrict__ out)                // [M][1024] f32
{
    __shared__ unsigned short As[32 * 512];
    const int tid = threadIdx.x;
    const int m0 = blockIdx.x * 32;
    const int c0 = blockIdx.y * 128;
    {
        int row = tid >> 3;
        const unsigned short* src = A + (size_t)(m0 + row) * 512;
        unsigned int base = row * 1024;
        unsigned int sw = (row & 7) << 4;
        #pragma unroll
        for (int c = 0; c < 8; ++c) {
            int col = (tid & 7) * 8 + c * 64;
            bf16x8 v = *reinterpret_cast<const bf16x8*>(src + col);
            *reinterpret_cast<bf16x8*>(
                reinterpret_cast<char*>(As) + ((base + col * 2) ^ sw)) = v;
        }
    }
    __syncthreads();
    const int w = tid >> 6, l = tid & 63;
    const int lr = l & 15, lkb = (l >> 4) * 8;
    f32x4 acc[2][2] = {};
    const int colbase = c0 + w * 32;
    const unsigned short* Wb = W + (size_t)(colbase + lr) * 512 + lkb;
    const unsigned int sw = (lr & 7) << 4;
    for (int ks = 0; ks < 16; ++ks) {
        unsigned int kb = (ks * 32 + lkb) * 2;
        bf16x8 a0 = *reinterpret_cast<const bf16x8*>(
            reinterpret_cast<const char*>(As) + ((lr * 1024 + kb) ^ sw));
        bf16x8 a1 = *reinterpret_cast<const bf16x8*>(
            reinterpret_cast<const char*>(As) + (((16 + lr) * 1024 + kb) ^ sw));
        #pragma unroll
        for (int nf = 0; nf < 2; ++nf) {
            bf16x8 b = *reinterpret_cast<const bf16x8*>(Wb + nf * 16 * 512 + ks * 32);
            acc[0][nf] = __builtin_amdgcn_mfma_f32_16x16x32_bf16(a0, b, acc[0][nf], 0, 0, 0);
            acc[1][nf] = __builtin_amdgcn_mfma_f32_16x16x32_bf16(a1, b, acc[1][nf], 0, 0, 0);
        }
    }
    const int qr = (l >> 4) * 4;
    #pragma unroll
    for (int nf = 0; nf < 2; ++nf) {
        int col = colbase + nf * 16 + lr;
        float bv = bias[col];
        #pragma unroll
        for (int mf = 0; mf < 2; ++mf)
            #pragma unroll
            for (int r = 0; r < 4; ++r)
                out[(size_t)(m0 + mf * 16 + qr + r) * 1024 + col] = acc[mf][nf][r] + bv;
    }
}

// ---------------- A = tanh(enc+dec) -> bf16, interleaved into out -----------
// Row r of out (4096 B): bytes [0,2048) hold A[r][0..1023] bf16.
__global__ __launch_bounds__(256) void k_tanhA(
    const float* __restrict__ enc_f,   // [1600][1024]
    const float* __restrict__ dec_f,   // [320][1024]
    char* __restrict__ outb)
{
    const int NG = 128000 * 128;       // 16B groups
    for (int g = blockIdx.x * 256 + threadIdx.x; g < NG; g += gridDim.x * 256) {
        int row = g >> 7, c8 = g & 127;
        int bt = row / 80;
        int u = row - bt * 80;
        int b = bt / 400;
        const float* ep = enc_f + (size_t)bt * 1024 + c8 * 8;
        const float* dp = dec_f + (size_t)(b * 80 + u) * 1024 + c8 * 8;
        float4 e0 = *(const float4*)ep, e1 = *(const float4*)(ep + 4);
        float4 f0 = *(const float4*)dp, f1 = *(const float4*)(dp + 4);
        uint4 pk;
        pk.x = (uint32_t)f2bf(fast_tanh(e0.x + f0.x)) | ((uint32_t)f2bf(fast_tanh(e0.y + f0.y)) << 16);
        pk.y = (uint32_t)f2bf(fast_tanh(e0.z + f0.z)) | ((uint32_t)f2bf(fast_tanh(e0.w + f0.w)) << 16);
        pk.z = (uint32_t)f2bf(fast_tanh(e1.x + f1.x)) | ((uint32_t)f2bf(fast_tanh(e1.y + f1.y)) << 16);
        pk.w = (uint32_t)f2bf(fast_tanh(e1.z + f1.z)) | ((uint32_t)f2bf(fast_tanh(e1.w + f1.w)) << 16);
        *(uint4*)(outb + (size_t)row * 4096 + c8 * 16) = pk;
    }
}

// ---------------- main GEMM: logits = A @ Wfc^T + bias (bf16 out) -----------
// 256x256 tile, BK=64, 1024 thr = 16 waves (4x4 grid, wave tile 64x64 ->
// acc 16xf32x4 = 64 VGPR -> 4 waves/SIMD occupancy). 2x64KB LDS dbuf,
// 4 phases/tile, counted vmcnt(2) boundaries (A of t+2 stays in flight),
// B(t+1) staged phases 1-2, A(t+2) staged after phase-3 barrier.
__global__ __launch_bounds__(1024, 2) void k_gemm(
    const unsigned short* __restrict__ Wfc,   // [1024][1024] bf16
    const float* __restrict__ bfc,            // [1024]
    char* __restrict__ outb)                  // A in [0,2048), logits out [2048,4096)
{
    extern __shared__ char smem[];            // 2 x (32KB A + 32KB B)
    const int tid = threadIdx.x;
    const int w = tid >> 6, l = tid & 63;
    const int lr = l & 15, q = l >> 4;
    const int wm = w >> 2, wn = w & 3;

    // grid 2000 = 8 XCDs x 250; within XCD: np fastest (4 N-panels share A)
    const int bid = (int)blockIdx.x;
    const int g = (bid & 7) * 250 + (bid >> 3);
    const size_t R0 = (size_t)(g >> 2) * 256;
    const int n0 = (g & 3) * 256;

    // staging source (pre-swizzled): per-thread chunks i=0,1 at
    // dest d = tid*16 + i*16384 (linear); L = d ^ (((d>>7)&7)<<4);
    // row = L>>7 (0..255), kb = L&127
    const char* sA[2]; const char* sB[2];
    #pragma unroll
    for (int i = 0; i < 2; ++i) {
        unsigned d = (unsigned)tid * 16 + i * 16384;
        unsigned L = d ^ (((d >> 7) & 7u) << 4);
        unsigned row = L >> 7, kb = L & 127u;
        sA[i] = outb + (R0 + row) * 4096 + kb;
        sB[i] = (const char*)Wfc + (size_t)(n0 + row) * 2048 + kb;
    }
    char* const dbase = smem + tid * 16;

#define STG_A(buf, T) do { \
    GLOAD_LDS16(sA[0] + (T) * 128, dbase + (buf)); \
    GLOAD_LDS16(sA[1] + (T) * 128, dbase + (buf) + 16384); \
} while (0)
#define STG_B0(buf, T) do { \
    GLOAD_LDS16(sB[0] + (T) * 128, dbase + (buf) + 32768); } while (0)
#define STG_B1(buf, T) do { \
    GLOAD_LDS16(sB[1] + (T) * 128, dbase + (buf) + 49152); } while (0)

    // fragment read offsets
    const unsigned key = (unsigned)((lr & 7) << 4);
    const unsigned kx0 = (unsigned)(q * 16) ^ key;
    const unsigned kx1 = (unsigned)(q * 16 + 64) ^ key;
    const unsigned abase = (unsigned)((wm * 64 + lr) * 128);            // + mf*2048
    const unsigned bbase = (unsigned)(32768 + (wn * 64 + lr) * 128);    // + nf*2048

    f32x4 acc[4][4] = {};   // [mf][nf]
    bf16x8 af[4], bfr[2];

#define LDA(h) do { \
    const unsigned _kx = (h) ? kx1 : kx0; \
    _Pragma("unroll") \
    for (int mf = 0; mf < 4; ++mf) \
        af[mf] = *(const bf16x8*)(smem + cb + abase + mf * 2048 + _kx); \
} while (0)
#define LDB2(h, gg) do { \
    const unsigned _kx = (h) ? kx1 : kx0; \
    bfr[0] = *(const bf16x8*)(smem + cb + bbase + ((gg) * 2 + 0) * 2048 + _kx); \
    bfr[1] = *(const bf16x8*)(smem + cb + bbase + ((gg) * 2 + 1) * 2048 + _kx); \
} while (0)
#define MFQ(gg) do { \
    __builtin_amdgcn_s_setprio(1); \
    _Pragma("unroll") \
    for (int j = 0; j < 2; ++j) \
        _Pragma("unroll") \
        for (int mf = 0; mf < 4; ++mf) \
            acc[mf][(gg) * 2 + j] = __builtin_amdgcn_mfma_f32_16x16x32_bf16( \
                bfr[j], af[mf], acc[mf][(gg) * 2 + j], 0, 0, 0); \
    __builtin_amdgcn_s_setprio(0); \
} while (0)
#define BAR __builtin_amdgcn_s_barrier()

    // prologue: tile0 A+B (buf0) + tile1 A (buf1, stays in flight)
    STG_A(0u, 0);
    STG_B0(0u, 0);
    STG_B1(0u, 0);
    STG_A(65536u, 1);
    asm volatile("s_waitcnt vmcnt(2)" ::: "memory");
    BAR;
    __builtin_amdgcn_sched_barrier(0);

    #pragma unroll 2
    for (int t = 0; t < 16; ++t) {
        const unsigned cb = (unsigned)(t & 1) * 65536u;
        const unsigned nb = cb ^ 65536u;
        const bool s1 = (t + 1 < 16), s2 = (t + 2 < 16);
        // phase 0
        LDA(0); LDB2(0, 0);
        BAR;
        MFQ(0);
        // phase 1: stage B-chunk0 of t+1 into non-current buf
        LDB2(0, 1);
        if (s1) STG_B0(nb, t + 1);
        BAR;
        MFQ(1);
        // phase 2: stage B-chunk1 of t+1
        LDA(1); LDB2(1, 1);
        if (s1) STG_B1(nb, t + 1);
        BAR;
        MFQ(1);
        // phase 3: after BAR, all waves' A-reads of cb complete -> overwrite
        // cb's A region with tile t+2 (longest-latency loads, ~5-phase cover)
        LDB2(1, 0);
        BAR;
        if (s2) STG_A(cb, t + 2);
        MFQ(0);
        // boundary: counted wait -- only t+2's 2 A-loads remain in flight
        if (t < 14) {
            asm volatile("s_waitcnt vmcnt(2)" ::: "memory");
            BAR;
            __builtin_amdgcn_sched_barrier(0);
        } else if (t == 14) {
            asm volatile("s_waitcnt vmcnt(0)" ::: "memory");
            BAR;
            __builtin_amdgcn_sched_barrier(0);
        }
    }
#undef LDA
#undef LDB2
#undef MFQ
#undef BAR
#undef STG_A
#undef STG_B0
#undef STG_B1

    // epilogue: bias + pack bf16 + 8B stores (4 consecutive vocab per lane)
    #pragma unroll
    for (int nf = 0; nf < 4; ++nf) {
        const int v = n0 + wn * 64 + nf * 16 + q * 4;
        float4 bv = *(const float4*)(bfc + v);
        #pragma unroll
        for (int mf = 0; mf < 4; ++mf) {
            f32x4 a = acc[mf][nf];
            uint2 pk;
            pk.x = (uint32_t)f2bf(a[0] + bv.x) | ((uint32_t)f2bf(a[1] + bv.y) << 16);
            pk.y = (uint32_t)f2bf(a[2] + bv.z) | ((uint32_t)f2bf(a[3] + bv.w) << 16);
            size_t m = R0 + (size_t)(wm * 64 + mf * 16 + lr);
            *(uint2*)(outb + m * 4096 + 2048 + (size_t)v * 2) = pk;
        }
    }
}

// ---------------- softmax/blank epilogue pass --------------------------------
__global__ __launch_bounds__(256) void k_softmax(char* __restrict__ outb)
{
    const int row = blockIdx.x * 4 + (threadIdx.x >> 6);
    const int l = threadIdx.x & 63;
    const char* lp = outb + (size_t)row * 4096 + 2048 + l * 32;
    uint4 wa = *(const uint4*)lp;
    uint4 wb = *(const uint4*)(lp + 16);
    float v[16];
    uint32_t wd[8] = { wa.x, wa.y, wa.z, wa.w, wb.x, wb.y, wb.z, wb.w };
    #pragma unroll
    for (int i = 0; i < 8; ++i) { v[2*i] = bf2f_lo(wd[i]); v[2*i+1] = bf2f_hi(wd[i]); }

    float l0 = __shfl(v[0], 0);
    float m = (l == 0) ? -3.0e38f : v[0];
    #pragma unroll
    for (int i = 1; i < 16; ++i) m = fmaxf(m, v[i]);
    #pragma unroll
    for (int s = 1; s < 64; s <<= 1) m = fmaxf(m, __shfl_xor(m, s));
    float s = (l == 0) ? 0.0f : __expf(v[0] - m);
    #pragma unroll
    for (int i = 1; i < 16; ++i) s += __expf(v[i] - m);
    #pragma unroll
    for (int sh = 1; sh < 64; sh <<= 1) s += __shfl_xor(s, sh);

    float lse = m + __logf(s);
    float fin = -lse - softplus_f(l0);     // log_sigmoid(-l0) - lse
    float f0v = -softplus_f(-l0);          // log_sigmoid(l0)

    float* op = (float*)(outb + (size_t)row * 4096) + l * 16;
    #pragma unroll
    for (int c = 0; c < 4; ++c) {
        float4 o;
        o.x = v[4*c+0] + fin; o.y = v[4*c+1] + fin;
        o.z = v[4*c+2] + fin; o.w = v[4*c+3] + fin;
        if (l == 0 && c == 0) o.x = f0v;
        *(float4*)(op + 4*c) = o;
    }
}

extern "C" void kernel_launch(void* const* d_in, const int* in_sizes, int n_in,
                              void* d_out, int out_size, void* d_ws, size_t ws_size,
                              hipStream_t stream)
{
    const float* encoder = (const float*)d_in[0]; // [4,400,512]
    const float* decoder = (const float*)d_in[1]; // [4,80,512]
    const float* W_enc   = (const float*)d_in[2]; // [1024,512]
    const float* b_enc   = (const float*)d_in[3]; // [1024]
    const float* W_dec   = (const float*)d_in[4]; // [1024,512]
    const float* b_dec   = (const float*)d_in[5]; // [1024]
    const float* W_fc    = (const float*)d_in[6]; // [1024,1024]
    const float* b_fc    = (const float*)d_in[7]; // [1024]
    char* outb = (char*)d_out;

    char* ws = (char*)d_ws;
    float*          enc_f  = (float*)(ws);                      // 1600*1024 f32
    float*          dec_f  = (float*)(ws + 6553600);            // 320*1024 f32
    unsigned short* Wfc_h  = (unsigned short*)(ws + 7864320);   // 1024*1024 bf16
    unsigned short* Wenc_h = (unsigned short*)(ws + 9961472);   // 1024*512 bf16
    unsigned short* Wdec_h = (unsigned short*)(ws + 11010048);  // 1024*512 bf16
    unsigned short* encI_h = (unsigned short*)(ws + 12058624);  // 1600*512 bf16
    unsigned short* decI_h = (unsigned short*)(ws + 13697024);  // 320*512 bf16

    const int nEnc = 4 * 400 * 512, nDec = 4 * 80 * 512;
    const int nWe = 1024 * 512, nWd = 1024 * 512, nWf = 1024 * 1024;
    const int totalF4 = (nEnc + nDec + nWe + nWd + nWf) >> 2;
    k_convert<<<(totalF4 + 255) / 256, 256, 0, stream>>>(
        encoder, decoder, W_enc, W_dec, W_fc,
        encI_h, decI_h, Wenc_h, Wdec_h, Wfc_h,
        nEnc, nDec, nWe, nWd, nWf);

    k_proj<<<dim3(1600 / 32, 8), 256, 0, stream>>>(encI_h, Wenc_h, b_enc, enc_f);
    k_proj<<<dim3(320 / 32, 8), 256, 0, stream>>>(decI_h, Wdec_h, b_dec, dec_f);

    k_tanhA<<<4096, 256, 0, stream>>>(enc_f, dec_f, outb);

    const int GEMM_SMEM = 131072;
    hipFuncSetAttribute(reinterpret_cast<const void*>(k_gemm),
                        hipFuncAttributeMaxDynamicSharedMemorySize, GEMM_SMEM);
    k_gemm<<<2000, 1024, GEMM_SMEM, stream>>>(Wfc_h, b_fc, outb);

    k_softmax<<<32000, 256, 0, stream>>>(outb);
}